// Round 12
// baseline (218.402 us; speedup 1.0000x reference)
//
#include <hip/hip_runtime.h>
#include <cmath>

// AttentionBlock: GroupNorm -> QKV 1x1 -> 8-head attention (L=1024) -> proj -> residual
// B=16, C=512, L=1024, 32 groups, 8 heads (ch=64). fp32 in/out, bf16 MFMA internally.

#define BATCH 16
#define CDIM 512
#define LDIM 1024
#define NQ (786432u)  // 1536*512
#define NP (262144u)  // 512*512

#define AS1 __attribute__((address_space(1)))
#define AS3 __attribute__((address_space(3)))

typedef unsigned short u16;
typedef u16 ushort8v __attribute__((ext_vector_type(8)));
typedef __bf16 bf16x8_t __attribute__((ext_vector_type(8)));
typedef float f32x4 __attribute__((ext_vector_type(4)));

__device__ __forceinline__ u16 f2bf(float f) {
  unsigned u = __float_as_uint(f);
  unsigned r = u + 0x7fffu + ((u >> 16) & 1u);  // RNE
  return (u16)(r >> 16);
}
__device__ __forceinline__ unsigned pack2(float a, float b) {
  return (unsigned)f2bf(a) | ((unsigned)f2bf(b) << 16);
}
// truncating bf16 pack: [hi16(a) | hi16(b)<<16] in one v_perm_b32
__device__ __forceinline__ unsigned pack2t(float a, float b) {
  return __builtin_amdgcn_perm(__float_as_uint(b), __float_as_uint(a), 0x07060302u);
}
__device__ __forceinline__ float fast_exp2(float x) {
#if __has_builtin(__builtin_amdgcn_exp2f)
  return __builtin_amdgcn_exp2f(x);  // v_exp_f32 = 2^x
#else
  return exp2f(x);
#endif
}
__device__ __forceinline__ f32x4 mfma16(ushort8v a, ushort8v b, f32x4 c) {
  return __builtin_amdgcn_mfma_f32_16x16x32_bf16(
      __builtin_bit_cast(bf16x8_t, a), __builtin_bit_cast(bf16x8_t, b), c, 0, 0, 0);
}
// async global->LDS, 16B/lane: LDS dst = wave-uniform base + lane*16
__device__ __forceinline__ void g2l16(const u16* g, u16* l) {
  __builtin_amdgcn_global_load_lds((const AS1 void*)g, (AS3 void*)l, 16, 0, 0);
}

// ---------------- prep: GroupNorm stats (blocks 0..511) + weight pack (512..1023) ----------
__global__ __launch_bounds__(256) void prep_kernel(const float* __restrict__ x,
                                                   const float* __restrict__ w,
                                                   const float* __restrict__ bvec,
                                                   const float* __restrict__ wq,
                                                   const float* __restrict__ wp,
                                                   float* __restrict__ scl,
                                                   float* __restrict__ sh,
                                                   u16* __restrict__ wqb,
                                                   u16* __restrict__ wpb) {
  int tid = threadIdx.x;
  if (blockIdx.x < 512) {
    int bg = blockIdx.x;
    int bb = bg >> 5, g = bg & 31;
    size_t base = ((size_t)bb * CDIM + g * 16) * LDIM;
    const float4* x4 = (const float4*)(x + base);
    float sum = 0.f, ss = 0.f;
#pragma unroll
    for (int i = 0; i < 16; ++i) {
      float4 v = x4[tid + 256 * i];
      sum += v.x + v.y + v.z + v.w;
      ss += v.x * v.x + v.y * v.y + v.z * v.z + v.w * v.w;
    }
#pragma unroll
    for (int off = 32; off; off >>= 1) {
      sum += __shfl_xor(sum, off);
      ss += __shfl_xor(ss, off);
    }
    __shared__ float rs[4], rq[4];
    int lane = tid & 63, wv = tid >> 6;
    if (lane == 0) { rs[wv] = sum; rq[wv] = ss; }
    __syncthreads();
    sum = rs[0] + rs[1] + rs[2] + rs[3];
    ss = rq[0] + rq[1] + rq[2] + rq[3];
    const float inv_n = 1.f / (16.f * 1024.f);
    float mean = sum * inv_n;
    float var = ss * inv_n - mean * mean;
    float rstd = rsqrtf(var + 1e-4f);
    if (tid < 16) {
      int c = g * 16 + tid;
      float s = w[c] * rstd;
      scl[bb * CDIM + c] = s;
      sh[bb * CDIM + c] = bvec[c] - mean * s;
    }
  } else {
    size_t i = (size_t)(blockIdx.x - 512) * 2048 + (size_t)tid * 8;
    const float* sp;
    u16* dp;
    size_t off;
    if (i < NQ) {
      off = i;
      sp = wq;
      dp = wqb;
    } else {
      off = i - NQ;
      sp = wp;
      dp = wpb;
    }
    float4 a = *(const float4*)&sp[off];
    float4 b = *(const float4*)&sp[off + 4];
    uint4 o;
    o.x = pack2(a.x, a.y);
    o.y = pack2(a.z, a.w);
    o.z = pack2(b.x, b.y);
    o.w = pack2(b.z, b.w);
    *(uint4*)&dp[off] = o;
  }
}

// ---------------- xpose: x[b][c][l] fp32 -> GN -> xnT[b][l][c] bf16 ----------------
__global__ __launch_bounds__(256) void xpose_kernel(const float* __restrict__ x,
                                                    const float* __restrict__ scl,
                                                    const float* __restrict__ sh,
                                                    u16* __restrict__ xnT) {
  __shared__ u16 T[64][72];  // [l][c], pad 72
  int b = blockIdx.z, c0 = blockIdx.y * 64, l0 = blockIdx.x * 64;
  int tid = threadIdx.x;
  int ci = tid >> 4, ljs = (tid & 15) * 4;
#pragma unroll
  for (int rep = 0; rep < 4; ++rep) {
    int c = rep * 16 + ci;
    float s_ = scl[b * CDIM + c0 + c];
    float h_ = sh[b * CDIM + c0 + c];
    float4 v = *(const float4*)&x[((size_t)b * CDIM + c0 + c) * LDIM + l0 + ljs];
    T[ljs + 0][c] = f2bf(v.x * s_ + h_);
    T[ljs + 1][c] = f2bf(v.y * s_ + h_);
    T[ljs + 2][c] = f2bf(v.z * s_ + h_);
    T[ljs + 3][c] = f2bf(v.w * s_ + h_);
  }
  __syncthreads();
  int lr = tid >> 2, cs8 = (tid & 3) * 16;
  uint4 o0 = *(const uint4*)&T[lr][cs8];
  uint4 o1 = *(const uint4*)&T[lr][cs8 + 8];
  size_t dst = ((size_t)b * LDIM + l0 + lr) * CDIM + c0 + cs8;
  *(uint4*)&xnT[dst] = o0;
  *(uint4*)&xnT[dst + 8] = o1;
}

// ---------------- MFMA GEMM, m97 anatomy: global_load_lds staging ----------------
// Both operands [out][k] bf16 row-major, K=512, BK=32, 128x128 tile, 2 barriers/iter.
// MODE 0: merged QKV (grid.y=12): m0<512 -> Q (transposed out qt[bh][t][c], scaled
//         by 0.125*log2e), <1024 -> K (transposed kt), else V -> v[b][c][l].
// MODE 1: proj -> fp32 out + bias + residual. X = avT [b][l][c].
template <int MODE>
__global__ __launch_bounds__(256) void gemm_mfma(
    const u16* __restrict__ Wb, const float* __restrict__ biasg,
    const u16* __restrict__ Xt, const float* __restrict__ resid,
    u16* __restrict__ qo, u16* __restrict__ ko,
    u16* __restrict__ vo, float* __restrict__ fo) {
  __shared__ __align__(16) u16 As_[128][32];  // [m][k] - unpadded (global_load_lds)
  __shared__ __align__(16) u16 Xs_[128][32];  // [n][k]
  int bb = blockIdx.z;
  int m0 = blockIdx.y * 128;
  int n0 = blockIdx.x * 128;
  int tid = threadIdx.x;
  int w = tid >> 6, lane = tid & 63, quad = lane >> 4, l15 = lane & 15;
  int wm = (w >> 1) * 64, wn = (w & 1) * 64;
  int srow = lane >> 2, scol = (lane & 3) * 8;
  const u16* Xb = Xt + (size_t)bb * LDIM * CDIM;  // [n][k=512]
  f32x4 acc[4][4] = {};  // QK path: [nsub][msub]; else: [msub][nsub]
  bool qkpath = (MODE == 0) && (m0 < 1024);

  for (int kk = 0; kk < 512; kk += 32) {
#pragma unroll
    for (int r = 0; r < 2; ++r) {
      int row = w * 32 + r * 16;
      g2l16(&Wb[(size_t)(m0 + row + srow) * 512 + kk + scol], &As_[row][0]);
      g2l16(&Xb[(size_t)(n0 + row + srow) * 512 + kk + scol], &Xs_[row][0]);
    }
    __syncthreads();
    ushort8v af[4], bfr[4];
#pragma unroll
    for (int i = 0; i < 4; ++i) af[i] = *(const ushort8v*)&As_[wm + i * 16 + l15][quad * 8];
#pragma unroll
    for (int i = 0; i < 4; ++i) bfr[i] = *(const ushort8v*)&Xs_[wn + i * 16 + l15][quad * 8];
    if (qkpath) {
#pragma unroll
      for (int i = 0; i < 4; ++i)
#pragma unroll
        for (int j = 0; j < 4; ++j) acc[j][i] = mfma16(bfr[j], af[i], acc[j][i]);  // D[n][m]
    } else {
#pragma unroll
      for (int i = 0; i < 4; ++i)
#pragma unroll
        for (int j = 0; j < 4; ++j) acc[i][j] = mfma16(af[i], bfr[j], acc[i][j]);  // D[m][n]
    }
    __syncthreads();
  }

  if (MODE == 0 && m0 < 1024) {
    bool isQ = (m0 < 512);
    float qscale = isQ ? (0.125f * 1.44269504f) : 1.0f;  // log2e folded into Q
    u16* dst = isQ ? qo : ko;
    int cbase0 = m0 - (isQ ? 0 : 512) + wm;
#pragma unroll
    for (int i = 0; i < 4; ++i) {
      int cg = cbase0 + i * 16 + l15;
      float bv = biasg[m0 + wm + i * 16 + l15];
      int hh = cg >> 6, cl = cg & 63;
      size_t rowbase = ((size_t)(bb * 8 + hh) * 1024) * 64 + cl;
#pragma unroll
      for (int j = 0; j < 4; ++j)
#pragma unroll
        for (int r = 0; r < 4; ++r) {
          int t = n0 + wn + j * 16 + quad * 4 + r;
          dst[rowbase + (size_t)t * 64] = f2bf((acc[j][i][r] + bv) * qscale);
        }
    }
  } else if (MODE == 0) {
#pragma unroll
    for (int i = 0; i < 4; ++i)
#pragma unroll
      for (int r = 0; r < 4; ++r) {
        int m_abs = m0 + wm + i * 16 + quad * 4 + r;
        float bv = biasg[m_abs];
        int cg = m_abs - 1024;
#pragma unroll
        for (int j = 0; j < 4; ++j) {
          int n = n0 + wn + j * 16 + l15;
          vo[((size_t)bb * CDIM + cg) * LDIM + n] = f2bf(acc[i][j][r] + bv);
        }
      }
  } else {
#pragma unroll
    for (int i = 0; i < 4; ++i)
#pragma unroll
      for (int r = 0; r < 4; ++r) {
        int m_abs = m0 + wm + i * 16 + quad * 4 + r;
        float bv = biasg[m_abs];
#pragma unroll
        for (int j = 0; j < 4; ++j) {
          int n = n0 + wn + j * 16 + l15;
          size_t off = ((size_t)bb * CDIM + m_abs) * LDIM + n;
          fo[off] = acc[i][j][r] + bv + resid[off];
        }
      }
  }
}

// ---------------- Attention: async-staged K/V (swizzled), ones-MFMA denominator ----------
// Grid (128 bh, 8 tblk): linear id % 8 == bh % 8 -> head-local XCD.
// Block: 4 waves x 32 t, full s-scan in 32-s chunks, double-buffered.
// Staging now via global_load_lds (16B/lane, LDS lane-linear); bank conflicts avoided
// by fetching XOR-swizzled global segments:
//   K LDS [32][64]: slot(row s, seg e) holds global seg e^(s&7)     -> frag reads 2-way (free)
//   V LDS [64][32]: slot(row c, seg e) holds global seg e^((c>>1)&3)-> frag reads 2-way (free)
// Softmax VALU stripped: p = v_exp_f32(score) (Q pre-scaled by 0.125*log2e), pack via
// v_perm (trunc), denominator = ones-row MFMA over the SAME bf16 P (numerator-consistent,
// zero VALU). PV computes O^T (P as A-operand) -> avT[b][l][c] coalesced.
__global__ __launch_bounds__(256) void attn_mfma(const u16* __restrict__ qt,
                                                 const u16* __restrict__ kt,
                                                 const u16* __restrict__ vv,
                                                 u16* __restrict__ avT) {
  __shared__ __align__(16) u16 Ks[2][32][64];  // 8 KB, unpadded (async dst)
  __shared__ __align__(16) u16 Vs[2][64][32];  // 8 KB, unpadded (async dst)
  __shared__ __align__(16) u16 Ps[4][32][40];  // per-wave P [t][s], 10 KB
  __shared__ float linv[4][32];                // per-wave inv-denominator by local t
  int bh = blockIdx.x;
  int t0b = blockIdx.y * 128;
  int b = bh >> 3, h = bh & 7;
  int tid = threadIdx.x;
  int w = tid >> 6, lane = tid & 63, quad = lane >> 4, l15 = lane & 15;
  int t0w = t0b + w * 32;
  size_t head = (size_t)bh * 65536;  // 1024*64
  const u16* kbase = kt + head;
  const u16* vbase = vv + head;

  // staging: thread -> K (row s=tid>>3, lds seg tid&7, global seg swizzled)
  int sK = tid >> 3;
  int gKseg = (tid & 7) ^ (sK & 7);
  int cV = tid >> 2;
  int gVseg = (tid & 3) ^ ((tid >> 3) & 3);  // (cV>>1)&3 == (tid>>3)&3
  u16* ldsK[2] = {&Ks[0][(w * 8)][0], &Ks[1][(w * 8)][0]};
  u16* ldsV[2] = {&Vs[0][(w * 16)][0], &Vs[1][(w * 16)][0]};

  ushort8v qf[2][2];
#pragma unroll
  for (int ts = 0; ts < 2; ++ts)
#pragma unroll
    for (int kc = 0; kc < 2; ++kc)
      qf[ts][kc] =
          *(const ushort8v*)&qt[head + (size_t)(t0w + ts * 16 + l15) * 64 + kc * 32 + quad * 8];

  ushort8v ones;
#pragma unroll
  for (int i = 0; i < 8; ++i) ones[i] = 0x3F80;  // bf16 1.0

  f32x4 Co[2][4] = {};  // [tsub][csub]: rows = t, cols = c (O^T)
  f32x4 Ls[2] = {};     // ones^T @ P : per-col (t) denominators

  // stage chunk 0 into buffer 0 (async)
  g2l16(&kbase[(size_t)sK * 64 + gKseg * 8], ldsK[0]);
  g2l16(&vbase[(size_t)cV * 1024 + gVseg * 8], ldsV[0]);
  __syncthreads();

  int cur = 0;
  for (int ci = 0; ci < 32; ++ci) {
    int sn = ((ci + 1) & 31) * 32;  // next chunk start (wraps; final load unused)
    int nxt = cur ^ 1;
    // issue next chunk's async loads now; drained at the barrier below
    g2l16(&kbase[(size_t)(sn + sK) * 64 + gKseg * 8], ldsK[nxt]);
    g2l16(&vbase[(size_t)cV * 1024 + sn + gVseg * 8], ldsV[nxt]);

    // ---- compute on buf[cur] ----
    ushort8v kf[2][2];
#pragma unroll
    for (int ms = 0; ms < 2; ++ms)
#pragma unroll
      for (int kc = 0; kc < 2; ++kc) {
        int s = ms * 16 + l15;
        int seg = kc * 4 + quad;  // global 8-u16 segment
        kf[ms][kc] = *(const ushort8v*)&Ks[cur][s][(seg ^ (s & 7)) * 8];
      }
    ushort8v vf[4];
#pragma unroll
    for (int cs = 0; cs < 4; ++cs) {
      int c = cs * 16 + l15;
      vf[cs] = *(const ushort8v*)&Vs[cur][c][(quad ^ ((c >> 1) & 3)) * 8];
    }

    f32x4 st[2][2];
#pragma unroll
    for (int ts = 0; ts < 2; ++ts)
#pragma unroll
      for (int ms = 0; ms < 2; ++ms) {
        f32x4 z = {};
        z = mfma16(kf[ms][0], qf[ts][0], z);
        st[ts][ms] = mfma16(kf[ms][1], qf[ts][1], z);
      }
#pragma unroll
    for (int ts = 0; ts < 2; ++ts) {
      float p0 = fast_exp2(st[ts][0].x), p1 = fast_exp2(st[ts][0].y);
      float p2 = fast_exp2(st[ts][0].z), p3 = fast_exp2(st[ts][0].w);
      float p4 = fast_exp2(st[ts][1].x), p5 = fast_exp2(st[ts][1].y);
      float p6 = fast_exp2(st[ts][1].z), p7 = fast_exp2(st[ts][1].w);
      uint2 u0, u1;
      u0.x = pack2t(p0, p1);
      u0.y = pack2t(p2, p3);
      u1.x = pack2t(p4, p5);
      u1.y = pack2t(p6, p7);
      *(uint2*)&Ps[w][ts * 16 + l15][quad * 4] = u0;
      *(uint2*)&Ps[w][ts * 16 + l15][16 + quad * 4] = u1;
    }
    // same-wave LDS RAW: ordered by lgkmcnt, no barrier needed
    ushort8v pb[2];
#pragma unroll
    for (int ts = 0; ts < 2; ++ts) pb[ts] = *(const ushort8v*)&Ps[w][ts * 16 + l15][quad * 8];
    // PV with P as A operand -> O^T; denominator on the matrix pipe
#pragma unroll
    for (int ts = 0; ts < 2; ++ts) {
#pragma unroll
      for (int cs = 0; cs < 4; ++cs) Co[ts][cs] = mfma16(pb[ts], vf[cs], Co[ts][cs]);
      Ls[ts] = mfma16(ones, pb[ts], Ls[ts]);
    }

    __syncthreads();  // drains async loads; protects buf[cur] until all reads done
    cur = nxt;
  }

  // denominator by col t = l15 (all acc rows equal); broadcast via LDS
#pragma unroll
  for (int ts = 0; ts < 2; ++ts)
    if (quad == 0) linv[w][ts * 16 + l15] = 1.f / Ls[ts][0];
  // same-wave LDS RAW: ordered by lgkmcnt
#pragma unroll
  for (int ts = 0; ts < 2; ++ts)
#pragma unroll
    for (int r = 0; r < 4; ++r) {
      int tl = ts * 16 + quad * 4 + r;
      float iv = linv[w][tl];
      size_t rowb = ((size_t)b * LDIM + t0w + tl) * CDIM + h * 64;
#pragma unroll
      for (int cs = 0; cs < 4; ++cs) avT[rowb + cs * 16 + l15] = f2bf(Co[ts][cs][r] * iv);
    }
}

extern "C" void kernel_launch(void* const* d_in, const int* in_sizes, int n_in,
                              void* d_out, int out_size, void* d_ws, size_t ws_size,
                              hipStream_t stream) {
  const float* x = (const float*)d_in[0];
  const float* norm_w = (const float*)d_in[1];
  const float* norm_b = (const float*)d_in[2];
  const float* qkv_w = (const float*)d_in[3];
  const float* qkv_b = (const float*)d_in[4];
  const float* proj_w = (const float*)d_in[5];
  const float* proj_b = (const float*)d_in[6];
  float* out = (float*)d_out;

  const size_t NE = (size_t)BATCH * CDIM * LDIM;  // 8.39M
  float* scl = (float*)d_ws;
  float* sh = scl + BATCH * CDIM;
  u16* qt = (u16*)(sh + BATCH * CDIM);  // [bh][t][c] bf16
  u16* kt = qt + NE;                    // [bh][s][c] bf16
  u16* vv = kt + NE;                    // [b][c][l]  bf16
  u16* av = vv + NE;                    // [b][l][c]  bf16 (O^T)
  u16* xn = av + NE;                    // [b][l][c]  bf16 (GN applied, transposed)
  u16* wqb = xn + NE;                   // [1536][512] bf16
  u16* wpb = wqb + NQ;                  // [512][512]  bf16

  prep_kernel<<<dim3(1024), dim3(256), 0, stream>>>(x, norm_w, norm_b, qkv_w, proj_w,
                                                    scl, sh, wqb, wpb);
  xpose_kernel<<<dim3(16, 8, BATCH), dim3(256), 0, stream>>>(x, scl, sh, xn);
  gemm_mfma<0><<<dim3(8, 12, BATCH), dim3(256), 0, stream>>>(
      wqb, qkv_b, xn, (const float*)nullptr, qt, kt, vv, (float*)nullptr);
  attn_mfma<<<dim3(128, 8), dim3(256), 0, stream>>>(qt, kt, vv, av);
  gemm_mfma<1><<<dim3(8, 4, BATCH), dim3(256), 0, stream>>>(
      wpb, proj_b, av, x, (u16*)nullptr, (u16*)nullptr, (u16*)nullptr, out);
}